// Round 3
// baseline (753.758 us; speedup 1.0000x reference)
//
#include <hip/hip_runtime.h>
#include <cmath>
#include <cstdint>
#include <cstddef>

#define HID 64
#define NGR 128            // B graphs
#define NTOT 131072        // 128 * 1024 nodes, fixed index space all layers
#define EDGES 1048576      // B * 1024 * 8
#define EPG 8192           // edges per graph
#define CPAD 9216          // padded CSR stride (u16): 8192 + 1024 worst-case pads
#define SENT 1024          // sentinel src index -> reads 0

// ---------- once: pack edges, degree hist, even-padded CSR, dinv ----------
__global__ __launch_bounds__(256) void pack_init(
    const int* __restrict__ ei, uint32_t* __restrict__ packed,
    uint16_t* __restrict__ csr_g, uint32_t* __restrict__ rs_g,
    float* __restrict__ dinv_g, float* __restrict__ sums3,
    float* __restrict__ readout) {
  __shared__ int hist[1024];
  __shared__ int part[256];
  __shared__ int cursor[1024];
  int b = blockIdx.x, t = threadIdx.x;
  for (int i = t; i < 1024; i += 256) hist[i] = 0;
  __syncthreads();
  int ebase = b * EPG, nbase = b << 10;
  for (int e = t; e < EPG; e += 256) {
    uint32_t s = (uint32_t)(ei[ebase + e] - nbase);
    uint32_t d = (uint32_t)(ei[EDGES + ebase + e] - nbase);
    packed[ebase + e] = s | (d << 10);
    atomicAdd(&hist[(int)d], 1);
  }
  __syncthreads();
  int h0 = hist[t * 4], h1 = hist[t * 4 + 1], h2 = hist[t * 4 + 2], h3 = hist[t * 4 + 3];
  // even-padded row lengths
  int p0 = h0 + (h0 & 1), p1 = h1 + (h1 & 1), p2 = h2 + (h2 & 1), p3 = h3 + (h3 & 1);
  int tot = p0 + p1 + p2 + p3;
  part[t] = tot;
  __syncthreads();
  for (int off = 1; off < 256; off <<= 1) {
    int v = (t >= off) ? part[t - off] : 0;
    __syncthreads();
    part[t] += v;
    __syncthreads();
  }
  int excl = part[t] - tot;
  int r0 = excl, r1 = r0 + p0, r2 = r1 + p1, r3 = r2 + p2;
  cursor[t * 4 + 0] = r0; cursor[t * 4 + 1] = r1;
  cursor[t * 4 + 2] = r2; cursor[t * 4 + 3] = r3;
  uint32_t* rg = rs_g + b * 1025;
  rg[t * 4 + 0] = r0; rg[t * 4 + 1] = r1; rg[t * 4 + 2] = r2; rg[t * 4 + 3] = r3;
  if (t == 255) rg[1024] = part[255];           // total padded length
  for (int i = t; i < 1024; i += 256)
    dinv_g[(b << 10) + i] = rsqrtf((float)hist[i] + 1.0f);
  __syncthreads();
  uint16_t* cg = csr_g + (size_t)b * CPAD;
  for (int e = t; e < EPG; e += 256) {
    uint32_t pk = packed[ebase + e];
    int d = (pk >> 10) & 1023;
    int idx = atomicAdd(&cursor[d], 1);
    cg[idx] = (uint16_t)(pk & 1023);
  }
  __syncthreads();
  // sentinel fill for odd rows (cursor[d] == pstart[d] + hist[d] now)
  for (int d = t; d < 1024; d += 256)
    if (hist[d] & 1) cg[cursor[d]] = (uint16_t)SENT;
  if (b < 3 && t < 128) sums3[b * 128 + t] = 0.0f;
  if (t < 128) readout[b * 128 + t] = 0.0f;
}

// ---------- streaming gemm, row-major X [N][DIN] (layer 0) ----------
// Block = 128 nodes x 32 channels (channel-split), thread = 4 nodes x 4 ch.
// W half staged in LDS (16 KB for DIN=128) -> 6 blocks/CU resident; grid 2048.
// Barrier-free k-loop; unroll 8 batches 32 independent global loads so 6
// waves/SIMD x deep ILP covers the ~900-cyc L3/HBM latency.
template<int DIN>
__global__ __launch_bounds__(256, 6) void gemm_rm(
    const float* __restrict__ X, const float* __restrict__ W,
    float* __restrict__ XWT) {
  __shared__ float sW[DIN * 32];       // 16 KB for DIN=128
  const int t = threadIdx.x;
  const int node0 = (blockIdx.x & 1023) * 128;
  const int ch0 = (blockIdx.x >> 10) * 32;
  const int c4 = (t & 7) * 4;
  const int n4 = (t >> 3) * 4;
  // stage W columns [ch0, ch0+32): sW[k*32 + c]
#pragma unroll
  for (int i = t; i < DIN * 8; i += 256)
    ((float4*)sW)[i] = *(const float4*)(W + (size_t)(i >> 3) * 64 + ch0 + (i & 7) * 4);
  __syncthreads();

  float acc[4][4];
#pragma unroll
  for (int i = 0; i < 4; i++)
#pragma unroll
    for (int c = 0; c < 4; c++) acc[i][c] = 0.0f;

  const float* xp = X + (size_t)(node0 + n4) * DIN;
#pragma unroll 8
  for (int k0 = 0; k0 < DIN; k0 += 4) {
    float x4[4][4];
#pragma unroll
    for (int i = 0; i < 4; i++) {
      float4 v = *(const float4*)(xp + (size_t)i * DIN + k0);
      x4[i][0] = v.x; x4[i][1] = v.y; x4[i][2] = v.z; x4[i][3] = v.w;
    }
#pragma unroll
    for (int j = 0; j < 4; j++) {
      float4 w = *(const float4*)(sW + (k0 + j) * 32 + c4);
      float wn[4] = {w.x, w.y, w.z, w.w};
#pragma unroll
      for (int i = 0; i < 4; i++)
#pragma unroll
        for (int c = 0; c < 4; c++)
          acc[i][c] = fmaf(x4[i][j], wn[c], acc[i][c]);
    }
  }
#pragma unroll
  for (int c = 0; c < 4; c++) {
    float* o = XWT + (size_t)(ch0 + c4 + c) * NTOT + node0 + n4;
    *(float4*)o = make_float4(acc[0][c], acc[1][c], acc[2][c], acc[3][c]);
  }
}

// ---------- streaming gemm, channel-major X [DIN][NTOT] (layers 1,2) ----------
// Same structure; X reads coalesced along nodes. 8 KB LDS -> 8 blocks/CU,
// grid 2048 = 256 CU x 8 exactly (no tail).
template<int DIN>
__global__ __launch_bounds__(256, 8) void gemm_cm(
    const float* __restrict__ X, const float* __restrict__ W,
    float* __restrict__ XWT) {
  __shared__ float sW[DIN * 32];       // 8 KB for DIN=64
  const int t = threadIdx.x;
  const int node0 = (blockIdx.x & 1023) * 128;
  const int ch0 = (blockIdx.x >> 10) * 32;
  const int c4 = (t & 7) * 4;
  const int n4 = (t >> 3) * 4;
#pragma unroll
  for (int i = t; i < DIN * 8; i += 256)
    ((float4*)sW)[i] = *(const float4*)(W + (size_t)(i >> 3) * 64 + ch0 + (i & 7) * 4);
  __syncthreads();

  float acc[4][4];
#pragma unroll
  for (int i = 0; i < 4; i++)
#pragma unroll
    for (int c = 0; c < 4; c++) acc[i][c] = 0.0f;

  const float* xp = X + node0 + n4;
#pragma unroll
  for (int k = 0; k < DIN; k++) {
    float4 xv = *(const float4*)(xp + (size_t)k * NTOT);
    float xn[4] = {xv.x, xv.y, xv.z, xv.w};
    float4 w = *(const float4*)(sW + k * 32 + c4);
    float wn[4] = {w.x, w.y, w.z, w.w};
#pragma unroll
    for (int i = 0; i < 4; i++)
#pragma unroll
      for (int c = 0; c < 4; c++)
        acc[i][c] = fmaf(xn[i], wn[c], acc[i][c]);
  }
#pragma unroll
  for (int c = 0; c < 4; c++) {
    float* o = XWT + (size_t)(ch0 + c4 + c) * NTOT + node0 + n4;
    *(float4*)o = make_float4(acc[0][c], acc[1][c], acc[2][c], acc[3][c]);
  }
}

// ---------- CSR aggregate (paired u32 src reads) + self-loop + bias + BN sums ----------
__global__ __launch_bounds__(1024, 8) void edge_agg(
    const uint16_t* __restrict__ csr_g, const uint32_t* __restrict__ rs_g,
    const float* __restrict__ dinv_g, const float* __restrict__ xwT,
    const float* __restrict__ bias, float* __restrict__ hT,
    float* __restrict__ sums) {
  __shared__ float xws[8 * 1028];      // prescaled xw*dinv; index 1024 = sentinel 0
  __shared__ float dv[1024];
  __shared__ uint32_t rs[1025];
  __shared__ uint32_t csr_s[CPAD / 2]; // 4608 u32 = 18.4 KB (pairs of u16 srcs)
  __shared__ float sredS[16][8], sredQ[16][8];
  const int g = blockIdx.x & 127;
  const int q = blockIdx.x >> 7;
  const int c0 = q * 8;
  const int t = threadIdx.x;
  const int gbase = g << 10;

  dv[t] = dinv_g[gbase + t];
  rs[t] = rs_g[g * 1025 + t];
  if (t == 0) rs[1024] = rs_g[g * 1025 + 1024];
  {
    const uint4* src4 = (const uint4*)(csr_g + (size_t)g * CPAD);
    ((uint4*)csr_s)[t] = src4[t];
    if (t < CPAD / 8 - 1024) ((uint4*)csr_s)[1024 + t] = src4[1024 + t];
  }
  for (int slot = t; slot < 2048; slot += 1024) {
    int c = slot >> 8, pos4 = (slot & 255) * 4;
    float4 v = *(const float4*)(xwT + (size_t)(c0 + c) * NTOT + gbase + pos4);
    float4 dd = *(const float4*)(dinv_g + gbase + pos4);
    v.x *= dd.x; v.y *= dd.y; v.z *= dd.z; v.w *= dd.w;
    *(float4*)(xws + c * 1028 + pos4) = v;
  }
  if (t < 32) xws[(t >> 2) * 1028 + 1024 + (t & 3)] = 0.0f;   // sentinel slots
  __syncthreads();

  const int c = t & 7, j = t >> 3;
  const float* xc = xws + c * 1028;
  const float bv = bias[c0 + c];
  float* hrow = hT + (size_t)(c0 + c) * NTOT + gbase;
  float S = 0.0f, Q = 0.0f;
  for (int d = j; d < 1024; d += 128) {
    float dvd = dv[d];
    if (dvd == 0.0f) continue;
    int e  = rs[d] >> 1;
    int e1 = rs[d + 1] >> 1;
    float a0 = 0.0f, a1 = 0.0f;
    for (; e < e1; e++) {
      uint32_t pk = csr_s[e];
      a0 += xc[pk & 0xFFFFu];
      a1 += xc[pk >> 16];
    }
    float hv = (a0 + a1 + xc[d]) * dvd + bv;
    hrow[d] = hv;
    S += hv; Q += hv * hv;
  }
#pragma unroll
  for (int m = 8; m < 64; m <<= 1) { S += __shfl_xor(S, m); Q += __shfl_xor(Q, m); }
  {
    int lane = t & 63, w = t >> 6;
    if (lane < 8) { sredS[w][lane] = S; sredQ[w][lane] = Q; }
  }
  __syncthreads();
  if (t < 8) {
    float a = 0.0f;
    for (int w2 = 0; w2 < 16; w2++) a += sredS[w2][t];
    atomicAdd(&sums[c0 + t], a);
  } else if (t < 16) {
    int cc = t - 8;
    float a = 0.0f;
    for (int w2 = 0; w2 < 16; w2++) a += sredQ[w2][cc];
    atomicAdd(&sums[64 + cc + c0], a);
  }
}

// ---------- scores: BN+ReLU+dot(p) per node; grid = NGR*4 x 256 ----------
__global__ __launch_bounds__(256) void score_kernel(
    const float* __restrict__ hT, const float* __restrict__ sums,
    const float* __restrict__ gamma, const float* __restrict__ beta,
    const float* __restrict__ p, const float* __restrict__ dinv_g,
    float* __restrict__ score, float* __restrict__ stanh_g, float inv_n) {
  __shared__ float ssc[64], ssh[64], sp[64];
  __shared__ float sipn;
  int b = blockIdx.x >> 2, seg = (blockIdx.x & 3) << 8;
  int t = threadIdx.x;
  int node = (b << 10) + seg + t;
  if (t < 64) {
    float mu = sums[t] * inv_n;
    float var = fmaxf(sums[64 + t] * inv_n - mu * mu, 0.0f);
    float sc = rsqrtf(var + 1e-5f) * gamma[t];
    ssc[t] = sc; ssh[t] = beta[t] - mu * sc;
    sp[t] = p[t];
  }
  __syncthreads();
  if (t == 0) {
    float s = 0.0f;
    for (int i = 0; i < 64; i++) s += sp[i] * sp[i];
    sipn = rsqrtf(s);
  }
  __syncthreads();
  const float* hp = hT + node;
  float s0 = 0.0f;
#pragma unroll 16
  for (int c = 0; c < 64; c++) {
    float y = fmaxf(fmaf(hp[(size_t)c * NTOT], ssc[c], ssh[c]), 0.0f);
    s0 = fmaf(y, sp[c], s0);
  }
  float v0 = s0 * sipn;
  score[node] = (dinv_g[node] > 0.0f) ? v0 : -INFINITY;
  stanh_g[node] = tanhf(v0);
}

// ---------- topk: 4 blocks/graph, 4-way j-split rank count -> kept mask ----------
__global__ __launch_bounds__(1024) void topk_kernel(
    const float* __restrict__ score, int* __restrict__ snext_g, int k) {
  __shared__ float __align__(16) ssc2[4 * 260];   // quarter q at offset q*260
  int b = blockIdx.x >> 2, p = blockIdx.x & 3;
  int t = threadIdx.x;
  int gbase = b << 10;
  float sv = score[gbase + t];
  ssc2[(t >> 8) * 260 + (t & 255)] = sv;
  __syncthreads();
  int il = t >> 2, jq = t & 3;
  int gi = p * 256 + il;
  float my = ssc2[(gi >> 8) * 260 + (gi & 255)];
  const float4* base = (const float4*)(ssc2 + jq * 260);
  int jbase = jq * 256;
  int r = 0;
#pragma unroll 8
  for (int m = 0; m < 64; m++) {
    float4 v = base[m];
    int j0 = jbase + m * 4;
    r += (v.x > my) || (v.x == my && (j0 + 0) < gi);
    r += (v.y > my) || (v.y == my && (j0 + 1) < gi);
    r += (v.z > my) || (v.z == my && (j0 + 2) < gi);
    r += (v.w > my) || (v.w == my && (j0 + 3) < gi);
  }
  r += __shfl_xor(r, 1);
  r += __shfl_xor(r, 2);
  if (jq == 0) snext_g[gbase + gi] = (r < k) ? 1 : 0;
}

// ---------- masked pool + readout accumulate + next-layer dinv (CSR walk) ----------
__global__ __launch_bounds__(256) void pool_kernel(
    const float* __restrict__ hT, const float* __restrict__ sums,
    const float* __restrict__ gamma, const float* __restrict__ beta,
    const float* __restrict__ stanh_g, const int* __restrict__ snext_g,
    const uint16_t* __restrict__ csr_g, const uint32_t* __restrict__ rs_g,
    float* __restrict__ xT_out, float* __restrict__ dinv_g,
    float* __restrict__ readout, int k, float inv_n, int hasNext) {
  __shared__ float ssc[64], ssh[64];
  __shared__ float sth[1024];
  __shared__ int skn[1025];            // [1024] = 0 for sentinel
  __shared__ float redS[4][8], redM[4][8];
  int g = blockIdx.x & 127, q = blockIdx.x >> 7;
  int t = threadIdx.x;
  int gbase = g << 10;
  if (t < 64) {
    float mu = sums[t] * inv_n;
    float var = fmaxf(sums[64 + t] * inv_n - mu * mu, 0.0f);
    float sc = rsqrtf(var + 1e-5f) * gamma[t];
    ssc[t] = sc; ssh[t] = beta[t] - mu * sc;
  }
  for (int i = t; i < 1024; i += 256) {
    sth[i] = stanh_g[gbase + i];
    skn[i] = snext_g[gbase + i];
  }
  if (t == 0) skn[1024] = 0;
  __syncthreads();
  int lane = t & 63, w = t >> 6;
#pragma unroll
  for (int i = 0; i < 8; i++) {
    int c = q * 8 + i;
    const float* hrow = hT + (size_t)c * NTOT + gbase;
    float* xrow = xT_out ? (xT_out + (size_t)c * NTOT + gbase) : nullptr;
    float scc = ssc[c], shh = ssh[c];
    float S = 0.0f, M = -INFINITY;
    for (int nd = t; nd < 1024; nd += 256) {
      bool kn = skn[nd] != 0;
      float y = fmaxf(fmaf(hrow[nd], scc, shh), 0.0f) * sth[nd];
      y = kn ? y : 0.0f;
      if (xrow) xrow[nd] = y;
      S += y;
      if (kn) M = fmaxf(M, y);
    }
#pragma unroll
    for (int m = 1; m < 64; m <<= 1) {
      S += __shfl_xor(S, m);
      M = fmaxf(M, __shfl_xor(M, m));
    }
    if (lane == 0) { redS[w][i] = S; redM[w][i] = M; }
  }
  if (hasNext && t < 128) {
    int d = q * 128 + t;
    if (skn[d]) {
      uint32_t e0 = rs_g[g * 1025 + d], e1 = rs_g[g * 1025 + d + 1];
      const uint16_t* row = csr_g + (size_t)g * CPAD;
      int cnt = 0;
      for (uint32_t e = e0; e < e1; e++) cnt += skn[row[e]];   // sentinel -> 0
      dinv_g[gbase + d] = rsqrtf((float)cnt + 1.0f);
    } else {
      dinv_g[gbase + d] = 0.0f;
    }
  }
  __syncthreads();
  if (t < 8) {
    float S = redS[0][t] + redS[1][t] + redS[2][t] + redS[3][t];
    readout[g * 128 + q * 8 + t] += S / (float)k;
  } else if (t < 16) {
    int i = t - 8;
    float M = fmaxf(fmaxf(redM[0][i], redM[1][i]), fmaxf(redM[2][i], redM[3][i]));
    readout[g * 128 + 64 + q * 8 + i] += M;
  }
}

// ---------------- out = readout @ Wm + bm ----------------
__global__ __launch_bounds__(256) void final_linear(
    const float* __restrict__ readout, const float* __restrict__ Wm,
    const float* __restrict__ bm, float* __restrict__ out) {
  int idx = blockIdx.x * 256 + threadIdx.x;
  if (idx >= NGR * 10) return;
  int b = idx / 10, o = idx - b * 10;
  float acc = bm[o];
  const float* r = readout + (size_t)b * 128;
  for (int c = 0; c < 128; c++) acc = fmaf(r[c], Wm[c * 10 + o], acc);
  out[idx] = acc;
}

extern "C" void kernel_launch(void* const* d_in, const int* in_sizes, int n_in,
                              void* d_out, int out_size, void* d_ws, size_t ws_size,
                              hipStream_t stream) {
  (void)in_sizes; (void)n_in; (void)out_size; (void)ws_size;
  const float* x  = (const float*)d_in[0];
  const int*   ei = (const int*)d_in[1];
  const float* Wk[3]  = {(const float*)d_in[2],  (const float*)d_in[7],  (const float*)d_in[12]};
  const float* bk[3]  = {(const float*)d_in[3],  (const float*)d_in[8],  (const float*)d_in[13]};
  const float* gk[3]  = {(const float*)d_in[4],  (const float*)d_in[9],  (const float*)d_in[14]};
  const float* btk[3] = {(const float*)d_in[5],  (const float*)d_in[10], (const float*)d_in[15]};
  const float* pk[3]  = {(const float*)d_in[6],  (const float*)d_in[11], (const float*)d_in[16]};
  const float* Wm = (const float*)d_in[17];
  const float* bm = (const float*)d_in[18];
  float* out = (float*)d_out;

  // ---- workspace carve (float units); feature buffers channel-major [64][NTOT] ----
  float* ws = (float*)d_ws;
  size_t off = 0;
  auto alloc = [&](size_t nfl) {
    float* ptr = ws + off;
    off += (nfl + 63) & ~(size_t)63;
    return ptr;
  };
  float* bufXW = alloc((size_t)NTOT * 64);
  float* bufH  = alloc((size_t)NTOT * 64);
  float* bufX  = alloc((size_t)NTOT * 64);
  float* dinv_g = alloc(NTOT);
  float* score  = alloc(NTOT);
  float* stanh_g = alloc(NTOT);
  int*   snext_g = (int*)alloc(NTOT);
  uint32_t* packed = (uint32_t*)alloc(EDGES);
  uint16_t* csr    = (uint16_t*)alloc((size_t)NGR * CPAD / 2);
  uint32_t* rs     = (uint32_t*)alloc(NGR * 1025);
  float* sums3 = alloc(3 * 128);
  float* readout = alloc(NGR * 2 * HID);

  pack_init<<<NGR, 256, 0, stream>>>(ei, packed, csr, rs, dinv_g, sums3, readout);

  const int   kk[3] = {820, 656, 525};
  const float invn[3] = {1.0f / (float)NTOT, 1.0f / (float)(NGR * 820),
                         1.0f / (float)(NGR * 656)};

  for (int L = 0; L < 3; L++) {
    float* sums = sums3 + L * 128;
    if (L == 0)
      gemm_rm<128><<<2048, 256, 0, stream>>>(x, Wk[0], bufXW);
    else
      gemm_cm<64><<<2048, 256, 0, stream>>>(bufX, Wk[L], bufXW);
    edge_agg<<<8 * NGR, 1024, 0, stream>>>(csr, rs, dinv_g, bufXW, bk[L], bufH, sums);
    score_kernel<<<4 * NGR, 256, 0, stream>>>(bufH, sums, gk[L], btk[L], pk[L],
                                              dinv_g, score, stanh_g, invn[L]);
    topk_kernel<<<4 * NGR, 1024, 0, stream>>>(score, snext_g, kk[L]);
    pool_kernel<<<8 * NGR, 256, 0, stream>>>(bufH, sums, gk[L], btk[L],
                                             stanh_g, snext_g, csr, rs,
                                             (L < 2) ? bufX : nullptr, dinv_g,
                                             readout, kk[L], invn[L],
                                             (L < 2) ? 1 : 0);
  }
  final_linear<<<5, 256, 0, stream>>>(readout, Wm, bm, out);
}

// Round 4
// 488.954 us; speedup vs baseline: 1.5416x; 1.5416x over previous
//
#include <hip/hip_runtime.h>
#include <cmath>
#include <cstdint>
#include <cstddef>

#define HID 64
#define NGR 128            // B graphs
#define NTOT 131072        // 128 * 1024 nodes, fixed index space all layers
#define EDGES 1048576      // B * 1024 * 8
#define EPG 8192           // edges per graph
#define CPAD 9216          // padded CSR stride (u16): 8192 + 1024 worst-case pads
#define SENT 1024          // sentinel src index -> reads 0

__device__ __forceinline__ float f4get(const float4& v, int j) {
  return j == 0 ? v.x : j == 1 ? v.y : j == 2 ? v.z : v.w;
}

// ---------- once: pack edges, degree hist, even-padded CSR, dinv ----------
__global__ __launch_bounds__(256) void pack_init(
    const int* __restrict__ ei, uint32_t* __restrict__ packed,
    uint16_t* __restrict__ csr_g, uint32_t* __restrict__ rs_g,
    float* __restrict__ dinv_g, float* __restrict__ sums3,
    float* __restrict__ readout) {
  __shared__ int hist[1024];
  __shared__ int part[256];
  __shared__ int cursor[1024];
  int b = blockIdx.x, t = threadIdx.x;
  for (int i = t; i < 1024; i += 256) hist[i] = 0;
  __syncthreads();
  int ebase = b * EPG, nbase = b << 10;
  for (int e = t; e < EPG; e += 256) {
    uint32_t s = (uint32_t)(ei[ebase + e] - nbase);
    uint32_t d = (uint32_t)(ei[EDGES + ebase + e] - nbase);
    packed[ebase + e] = s | (d << 10);
    atomicAdd(&hist[(int)d], 1);
  }
  __syncthreads();
  int h0 = hist[t * 4], h1 = hist[t * 4 + 1], h2 = hist[t * 4 + 2], h3 = hist[t * 4 + 3];
  // even-padded row lengths
  int p0 = h0 + (h0 & 1), p1 = h1 + (h1 & 1), p2 = h2 + (h2 & 1), p3 = h3 + (h3 & 1);
  int tot = p0 + p1 + p2 + p3;
  part[t] = tot;
  __syncthreads();
  for (int off = 1; off < 256; off <<= 1) {
    int v = (t >= off) ? part[t - off] : 0;
    __syncthreads();
    part[t] += v;
    __syncthreads();
  }
  int excl = part[t] - tot;
  int r0 = excl, r1 = r0 + p0, r2 = r1 + p1, r3 = r2 + p2;
  cursor[t * 4 + 0] = r0; cursor[t * 4 + 1] = r1;
  cursor[t * 4 + 2] = r2; cursor[t * 4 + 3] = r3;
  uint32_t* rg = rs_g + b * 1025;
  rg[t * 4 + 0] = r0; rg[t * 4 + 1] = r1; rg[t * 4 + 2] = r2; rg[t * 4 + 3] = r3;
  if (t == 255) rg[1024] = part[255];           // total padded length
  for (int i = t; i < 1024; i += 256)
    dinv_g[(b << 10) + i] = rsqrtf((float)hist[i] + 1.0f);
  __syncthreads();
  uint16_t* cg = csr_g + (size_t)b * CPAD;
  for (int e = t; e < EPG; e += 256) {
    uint32_t pk = packed[ebase + e];
    int d = (pk >> 10) & 1023;
    int idx = atomicAdd(&cursor[d], 1);
    cg[idx] = (uint16_t)(pk & 1023);
  }
  __syncthreads();
  // sentinel fill for odd rows (cursor[d] == pstart[d] + hist[d] now)
  for (int d = t; d < 1024; d += 256)
    if (hist[d] & 1) cg[cursor[d]] = (uint16_t)SENT;
  if (b < 3 && t < 128) sums3[b * 128 + t] = 0.0f;
  if (t < 128) readout[b * 128 + t] = 0.0f;
}

// ---------- streaming gemm, row-major X [N][DIN] (layer 0) ----------
// Block = 128 nodes x 64 ch, thread = 4 nodes x 8 ch, grid 1024 (4 blk/CU).
// W fully LDS-resident (32 KB); barrier-free k-loop, software-pipelined with
// named xa/xb register double-buffer: step s+1's 4 loads are issued BEFORE
// step s's FMAs, keeping a full load batch in flight per wave (Little's law
// against ~600-700cyc L2/L3 latency). (256,4): no VGPR squeeze -> no spill.
template<int DIN>
__global__ __launch_bounds__(256, 4) void gemm_rm(
    const float* __restrict__ X, const float* __restrict__ W,
    float* __restrict__ XWT) {
  __shared__ float sW[DIN * 64];       // 32 KB for DIN=128
  const int t = threadIdx.x;
  const int c8 = (t & 7) * 8;
  const int n4 = (t >> 3) * 4;
  const int node0 = blockIdx.x * 128;
#pragma unroll
  for (int i = t; i < DIN * 16; i += 256)
    ((float4*)sW)[i] = ((const float4*)W)[i];
  __syncthreads();

  float acc[4][8];
#pragma unroll
  for (int i = 0; i < 4; i++)
#pragma unroll
    for (int c = 0; c < 8; c++) acc[i][c] = 0.0f;

  const float* xp = X + (size_t)(node0 + n4) * DIN;

  auto comp = [&](const float4& a0, const float4& a1, const float4& a2,
                  const float4& a3, int kb) {
#pragma unroll
    for (int j = 0; j < 4; j++) {
      float4 w0 = *(const float4*)(sW + (kb + j) * 64 + c8);
      float4 w1 = *(const float4*)(sW + (kb + j) * 64 + c8 + 4);
      float wn[8] = {w0.x, w0.y, w0.z, w0.w, w1.x, w1.y, w1.z, w1.w};
      float xn[4] = {f4get(a0, j), f4get(a1, j), f4get(a2, j), f4get(a3, j)};
#pragma unroll
      for (int i = 0; i < 4; i++)
#pragma unroll
        for (int c = 0; c < 8; c++)
          acc[i][c] = fmaf(xn[i], wn[c], acc[i][c]);
    }
  };

  float4 xa0 = *(const float4*)(xp + 0 * DIN);
  float4 xa1 = *(const float4*)(xp + 1 * DIN);
  float4 xa2 = *(const float4*)(xp + 2 * DIN);
  float4 xa3 = *(const float4*)(xp + 3 * DIN);
  for (int k0 = 0; k0 < DIN; k0 += 8) {
    const int kp1 = k0 + 4;
    float4 xb0 = *(const float4*)(xp + 0 * DIN + kp1);
    float4 xb1 = *(const float4*)(xp + 1 * DIN + kp1);
    float4 xb2 = *(const float4*)(xp + 2 * DIN + kp1);
    float4 xb3 = *(const float4*)(xp + 3 * DIN + kp1);
    comp(xa0, xa1, xa2, xa3, k0);
    const int kp2 = (k0 + 8 < DIN) ? k0 + 8 : 0;   // wrap: harmless reload
    xa0 = *(const float4*)(xp + 0 * DIN + kp2);
    xa1 = *(const float4*)(xp + 1 * DIN + kp2);
    xa2 = *(const float4*)(xp + 2 * DIN + kp2);
    xa3 = *(const float4*)(xp + 3 * DIN + kp2);
    comp(xb0, xb1, xb2, xb3, kp1);
  }
#pragma unroll
  for (int c = 0; c < 8; c++) {
    float* o = XWT + (size_t)(c8 + c) * NTOT + node0 + n4;
    *(float4*)o = make_float4(acc[0][c], acc[1][c], acc[2][c], acc[3][c]);
  }
}

// ---------- streaming gemm, channel-major X [DIN][NTOT] (layers 1,2) ----------
// Same pipeline structure; per k one float4 of 4 nodes (coalesced 128B/wave,
// 8-lane broadcast). Steps of 4 k, xa/xb double-buffer. X read exactly once.
template<int DIN>
__global__ __launch_bounds__(256, 4) void gemm_cm(
    const float* __restrict__ X, const float* __restrict__ W,
    float* __restrict__ XWT) {
  __shared__ float sW[DIN * 64];       // 16 KB for DIN=64
  const int t = threadIdx.x;
  const int c8 = (t & 7) * 8;
  const int n4 = (t >> 3) * 4;
  const int node0 = blockIdx.x * 128;
#pragma unroll
  for (int i = t; i < DIN * 16; i += 256)
    ((float4*)sW)[i] = ((const float4*)W)[i];
  __syncthreads();

  float acc[4][8];
#pragma unroll
  for (int i = 0; i < 4; i++)
#pragma unroll
    for (int c = 0; c < 8; c++) acc[i][c] = 0.0f;

  const float* xp = X + node0 + n4;

  // here float4 = 4 NODES at one k; comp consumes 4 consecutive k's
  auto comp = [&](const float4& a0, const float4& a1, const float4& a2,
                  const float4& a3, int kb) {
#pragma unroll
    for (int j = 0; j < 4; j++) {
      float4 w0 = *(const float4*)(sW + (kb + j) * 64 + c8);
      float4 w1 = *(const float4*)(sW + (kb + j) * 64 + c8 + 4);
      float wn[8] = {w0.x, w0.y, w0.z, w0.w, w1.x, w1.y, w1.z, w1.w};
      const float4& aj = j == 0 ? a0 : j == 1 ? a1 : j == 2 ? a2 : a3;
      float xn[4] = {aj.x, aj.y, aj.z, aj.w};
#pragma unroll
      for (int i = 0; i < 4; i++)
#pragma unroll
        for (int c = 0; c < 8; c++)
          acc[i][c] = fmaf(xn[i], wn[c], acc[i][c]);
    }
  };

  float4 xa0 = *(const float4*)(xp + (size_t)0 * NTOT);
  float4 xa1 = *(const float4*)(xp + (size_t)1 * NTOT);
  float4 xa2 = *(const float4*)(xp + (size_t)2 * NTOT);
  float4 xa3 = *(const float4*)(xp + (size_t)3 * NTOT);
  for (int k0 = 0; k0 < DIN; k0 += 8) {
    const int kp1 = k0 + 4;
    float4 xb0 = *(const float4*)(xp + (size_t)(kp1 + 0) * NTOT);
    float4 xb1 = *(const float4*)(xp + (size_t)(kp1 + 1) * NTOT);
    float4 xb2 = *(const float4*)(xp + (size_t)(kp1 + 2) * NTOT);
    float4 xb3 = *(const float4*)(xp + (size_t)(kp1 + 3) * NTOT);
    comp(xa0, xa1, xa2, xa3, k0);
    const int kp2 = (k0 + 8 < DIN) ? k0 + 8 : 0;   // wrap: harmless reload
    xa0 = *(const float4*)(xp + (size_t)(kp2 + 0) * NTOT);
    xa1 = *(const float4*)(xp + (size_t)(kp2 + 1) * NTOT);
    xa2 = *(const float4*)(xp + (size_t)(kp2 + 2) * NTOT);
    xa3 = *(const float4*)(xp + (size_t)(kp2 + 3) * NTOT);
    comp(xb0, xb1, xb2, xb3, kp1);
  }
#pragma unroll
  for (int c = 0; c < 8; c++) {
    float* o = XWT + (size_t)(c8 + c) * NTOT + node0 + n4;
    *(float4*)o = make_float4(acc[0][c], acc[1][c], acc[2][c], acc[3][c]);
  }
}

// ---------- CSR aggregate (paired u32 src reads) + self-loop + bias + BN sums ----------
__global__ __launch_bounds__(1024, 8) void edge_agg(
    const uint16_t* __restrict__ csr_g, const uint32_t* __restrict__ rs_g,
    const float* __restrict__ dinv_g, const float* __restrict__ xwT,
    const float* __restrict__ bias, float* __restrict__ hT,
    float* __restrict__ sums) {
  __shared__ float xws[8 * 1028];      // prescaled xw*dinv; index 1024 = sentinel 0
  __shared__ float dv[1024];
  __shared__ uint32_t rs[1025];
  __shared__ uint32_t csr_s[CPAD / 2]; // 4608 u32 = 18.4 KB (pairs of u16 srcs)
  __shared__ float sredS[16][8], sredQ[16][8];
  const int g = blockIdx.x & 127;
  const int q = blockIdx.x >> 7;
  const int c0 = q * 8;
  const int t = threadIdx.x;
  const int gbase = g << 10;

  dv[t] = dinv_g[gbase + t];
  rs[t] = rs_g[g * 1025 + t];
  if (t == 0) rs[1024] = rs_g[g * 1025 + 1024];
  {
    const uint4* src4 = (const uint4*)(csr_g + (size_t)g * CPAD);
    ((uint4*)csr_s)[t] = src4[t];
    if (t < CPAD / 8 - 1024) ((uint4*)csr_s)[1024 + t] = src4[1024 + t];
  }
  for (int slot = t; slot < 2048; slot += 1024) {
    int c = slot >> 8, pos4 = (slot & 255) * 4;
    float4 v = *(const float4*)(xwT + (size_t)(c0 + c) * NTOT + gbase + pos4);
    float4 dd = *(const float4*)(dinv_g + gbase + pos4);
    v.x *= dd.x; v.y *= dd.y; v.z *= dd.z; v.w *= dd.w;
    *(float4*)(xws + c * 1028 + pos4) = v;
  }
  if (t < 32) xws[(t >> 2) * 1028 + 1024 + (t & 3)] = 0.0f;   // sentinel slots
  __syncthreads();

  const int c = t & 7, j = t >> 3;
  const float* xc = xws + c * 1028;
  const float bv = bias[c0 + c];
  float* hrow = hT + (size_t)(c0 + c) * NTOT + gbase;
  float S = 0.0f, Q = 0.0f;
  for (int d = j; d < 1024; d += 128) {
    float dvd = dv[d];
    if (dvd == 0.0f) continue;
    int e  = rs[d] >> 1;
    int e1 = rs[d + 1] >> 1;
    float a0 = 0.0f, a1 = 0.0f;
    for (; e < e1; e++) {
      uint32_t pk = csr_s[e];
      a0 += xc[pk & 0xFFFFu];
      a1 += xc[pk >> 16];
    }
    float hv = (a0 + a1 + xc[d]) * dvd + bv;
    hrow[d] = hv;
    S += hv; Q += hv * hv;
  }
#pragma unroll
  for (int m = 8; m < 64; m <<= 1) { S += __shfl_xor(S, m); Q += __shfl_xor(Q, m); }
  {
    int lane = t & 63, w = t >> 6;
    if (lane < 8) { sredS[w][lane] = S; sredQ[w][lane] = Q; }
  }
  __syncthreads();
  if (t < 8) {
    float a = 0.0f;
    for (int w2 = 0; w2 < 16; w2++) a += sredS[w2][t];
    atomicAdd(&sums[c0 + t], a);
  } else if (t < 16) {
    int cc = t - 8;
    float a = 0.0f;
    for (int w2 = 0; w2 < 16; w2++) a += sredQ[w2][cc];
    atomicAdd(&sums[64 + cc + c0], a);
  }
}

// ---------- scores: BN+ReLU+dot(p) per node; grid = NGR*4 x 256 ----------
__global__ __launch_bounds__(256) void score_kernel(
    const float* __restrict__ hT, const float* __restrict__ sums,
    const float* __restrict__ gamma, const float* __restrict__ beta,
    const float* __restrict__ p, const float* __restrict__ dinv_g,
    float* __restrict__ score, float* __restrict__ stanh_g, float inv_n) {
  __shared__ float ssc[64], ssh[64], sp[64];
  __shared__ float sipn;
  int b = blockIdx.x >> 2, seg = (blockIdx.x & 3) << 8;
  int t = threadIdx.x;
  int node = (b << 10) + seg + t;
  if (t < 64) {
    float mu = sums[t] * inv_n;
    float var = fmaxf(sums[64 + t] * inv_n - mu * mu, 0.0f);
    float sc = rsqrtf(var + 1e-5f) * gamma[t];
    ssc[t] = sc; ssh[t] = beta[t] - mu * sc;
    sp[t] = p[t];
  }
  __syncthreads();
  if (t == 0) {
    float s = 0.0f;
    for (int i = 0; i < 64; i++) s += sp[i] * sp[i];
    sipn = rsqrtf(s);
  }
  __syncthreads();
  const float* hp = hT + node;
  float s0 = 0.0f;
#pragma unroll 16
  for (int c = 0; c < 64; c++) {
    float y = fmaxf(fmaf(hp[(size_t)c * NTOT], ssc[c], ssh[c]), 0.0f);
    s0 = fmaf(y, sp[c], s0);
  }
  float v0 = s0 * sipn;
  score[node] = (dinv_g[node] > 0.0f) ? v0 : -INFINITY;
  stanh_g[node] = tanhf(v0);
}

// ---------- topk: 4 blocks/graph, 4-way j-split rank count -> kept mask ----------
__global__ __launch_bounds__(1024) void topk_kernel(
    const float* __restrict__ score, int* __restrict__ snext_g, int k) {
  __shared__ float __align__(16) ssc2[4 * 260];   // quarter q at offset q*260
  int b = blockIdx.x >> 2, p = blockIdx.x & 3;
  int t = threadIdx.x;
  int gbase = b << 10;
  float sv = score[gbase + t];
  ssc2[(t >> 8) * 260 + (t & 255)] = sv;
  __syncthreads();
  int il = t >> 2, jq = t & 3;
  int gi = p * 256 + il;
  float my = ssc2[(gi >> 8) * 260 + (gi & 255)];
  const float4* base = (const float4*)(ssc2 + jq * 260);
  int jbase = jq * 256;
  int r = 0;
#pragma unroll 8
  for (int m = 0; m < 64; m++) {
    float4 v = base[m];
    int j0 = jbase + m * 4;
    r += (v.x > my) || (v.x == my && (j0 + 0) < gi);
    r += (v.y > my) || (v.y == my && (j0 + 1) < gi);
    r += (v.z > my) || (v.z == my && (j0 + 2) < gi);
    r += (v.w > my) || (v.w == my && (j0 + 3) < gi);
  }
  r += __shfl_xor(r, 1);
  r += __shfl_xor(r, 2);
  if (jq == 0) snext_g[gbase + gi] = (r < k) ? 1 : 0;
}

// ---------- masked pool + readout accumulate + next-layer dinv (CSR walk) ----------
__global__ __launch_bounds__(256) void pool_kernel(
    const float* __restrict__ hT, const float* __restrict__ sums,
    const float* __restrict__ gamma, const float* __restrict__ beta,
    const float* __restrict__ stanh_g, const int* __restrict__ snext_g,
    const uint16_t* __restrict__ csr_g, const uint32_t* __restrict__ rs_g,
    float* __restrict__ xT_out, float* __restrict__ dinv_g,
    float* __restrict__ readout, int k, float inv_n, int hasNext) {
  __shared__ float ssc[64], ssh[64];
  __shared__ float sth[1024];
  __shared__ int skn[1025];            // [1024] = 0 for sentinel
  __shared__ float redS[4][8], redM[4][8];
  int g = blockIdx.x & 127, q = blockIdx.x >> 7;
  int t = threadIdx.x;
  int gbase = g << 10;
  if (t < 64) {
    float mu = sums[t] * inv_n;
    float var = fmaxf(sums[64 + t] * inv_n - mu * mu, 0.0f);
    float sc = rsqrtf(var + 1e-5f) * gamma[t];
    ssc[t] = sc; ssh[t] = beta[t] - mu * sc;
  }
  for (int i = t; i < 1024; i += 256) {
    sth[i] = stanh_g[gbase + i];
    skn[i] = snext_g[gbase + i];
  }
  if (t == 0) skn[1024] = 0;
  __syncthreads();
  int lane = t & 63, w = t >> 6;
#pragma unroll
  for (int i = 0; i < 8; i++) {
    int c = q * 8 + i;
    const float* hrow = hT + (size_t)c * NTOT + gbase;
    float* xrow = xT_out ? (xT_out + (size_t)c * NTOT + gbase) : nullptr;
    float scc = ssc[c], shh = ssh[c];
    float S = 0.0f, M = -INFINITY;
    for (int nd = t; nd < 1024; nd += 256) {
      bool kn = skn[nd] != 0;
      float y = fmaxf(fmaf(hrow[nd], scc, shh), 0.0f) * sth[nd];
      y = kn ? y : 0.0f;
      if (xrow) xrow[nd] = y;
      S += y;
      if (kn) M = fmaxf(M, y);
    }
#pragma unroll
    for (int m = 1; m < 64; m <<= 1) {
      S += __shfl_xor(S, m);
      M = fmaxf(M, __shfl_xor(M, m));
    }
    if (lane == 0) { redS[w][i] = S; redM[w][i] = M; }
  }
  if (hasNext && t < 128) {
    int d = q * 128 + t;
    if (skn[d]) {
      uint32_t e0 = rs_g[g * 1025 + d], e1 = rs_g[g * 1025 + d + 1];
      const uint16_t* row = csr_g + (size_t)g * CPAD;
      int cnt = 0;
      for (uint32_t e = e0; e < e1; e++) cnt += skn[row[e]];   // sentinel -> 0
      dinv_g[gbase + d] = rsqrtf((float)cnt + 1.0f);
    } else {
      dinv_g[gbase + d] = 0.0f;
    }
  }
  __syncthreads();
  if (t < 8) {
    float S = redS[0][t] + redS[1][t] + redS[2][t] + redS[3][t];
    readout[g * 128 + q * 8 + t] += S / (float)k;
  } else if (t < 16) {
    int i = t - 8;
    float M = fmaxf(fmaxf(redM[0][i], redM[1][i]), fmaxf(redM[2][i], redM[3][i]));
    readout[g * 128 + 64 + q * 8 + i] += M;
  }
}

// ---------------- out = readout @ Wm + bm ----------------
__global__ __launch_bounds__(256) void final_linear(
    const float* __restrict__ readout, const float* __restrict__ Wm,
    const float* __restrict__ bm, float* __restrict__ out) {
  int idx = blockIdx.x * 256 + threadIdx.x;
  if (idx >= NGR * 10) return;
  int b = idx / 10, o = idx - b * 10;
  float acc = bm[o];
  const float* r = readout + (size_t)b * 128;
  for (int c = 0; c < 128; c++) acc = fmaf(r[c], Wm[c * 10 + o], acc);
  out[idx] = acc;
}

extern "C" void kernel_launch(void* const* d_in, const int* in_sizes, int n_in,
                              void* d_out, int out_size, void* d_ws, size_t ws_size,
                              hipStream_t stream) {
  (void)in_sizes; (void)n_in; (void)out_size; (void)ws_size;
  const float* x  = (const float*)d_in[0];
  const int*   ei = (const int*)d_in[1];
  const float* Wk[3]  = {(const float*)d_in[2],  (const float*)d_in[7],  (const float*)d_in[12]};
  const float* bk[3]  = {(const float*)d_in[3],  (const float*)d_in[8],  (const float*)d_in[13]};
  const float* gk[3]  = {(const float*)d_in[4],  (const float*)d_in[9],  (const float*)d_in[14]};
  const float* btk[3] = {(const float*)d_in[5],  (const float*)d_in[10], (const float*)d_in[15]};
  const float* pk[3]  = {(const float*)d_in[6],  (const float*)d_in[11], (const float*)d_in[16]};
  const float* Wm = (const float*)d_in[17];
  const float* bm = (const float*)d_in[18];
  float* out = (float*)d_out;

  // ---- workspace carve (float units); feature buffers channel-major [64][NTOT] ----
  float* ws = (float*)d_ws;
  size_t off = 0;
  auto alloc = [&](size_t nfl) {
    float* ptr = ws + off;
    off += (nfl + 63) & ~(size_t)63;
    return ptr;
  };
  float* bufXW = alloc((size_t)NTOT * 64);
  float* bufH  = alloc((size_t)NTOT * 64);
  float* bufX  = alloc((size_t)NTOT * 64);
  float* dinv_g = alloc(NTOT);
  float* score  = alloc(NTOT);
  float* stanh_g = alloc(NTOT);
  int*   snext_g = (int*)alloc(NTOT);
  uint32_t* packed = (uint32_t*)alloc(EDGES);
  uint16_t* csr    = (uint16_t*)alloc((size_t)NGR * CPAD / 2);
  uint32_t* rs     = (uint32_t*)alloc(NGR * 1025);
  float* sums3 = alloc(3 * 128);
  float* readout = alloc(NGR * 2 * HID);

  pack_init<<<NGR, 256, 0, stream>>>(ei, packed, csr, rs, dinv_g, sums3, readout);

  const int   kk[3] = {820, 656, 525};
  const float invn[3] = {1.0f / (float)NTOT, 1.0f / (float)(NGR * 820),
                         1.0f / (float)(NGR * 656)};

  for (int L = 0; L < 3; L++) {
    float* sums = sums3 + L * 128;
    if (L == 0)
      gemm_rm<128><<<NTOT / 128, 256, 0, stream>>>(x, Wk[0], bufXW);
    else
      gemm_cm<64><<<NTOT / 128, 256, 0, stream>>>(bufX, Wk[L], bufXW);
    edge_agg<<<8 * NGR, 1024, 0, stream>>>(csr, rs, dinv_g, bufXW, bk[L], bufH, sums);
    score_kernel<<<4 * NGR, 256, 0, stream>>>(bufH, sums, gk[L], btk[L], pk[L],
                                              dinv_g, score, stanh_g, invn[L]);
    topk_kernel<<<4 * NGR, 1024, 0, stream>>>(score, snext_g, kk[L]);
    pool_kernel<<<8 * NGR, 256, 0, stream>>>(bufH, sums, gk[L], btk[L],
                                             stanh_g, snext_g, csr, rs,
                                             (L < 2) ? bufX : nullptr, dinv_g,
                                             readout, kk[L], invn[L],
                                             (L < 2) ? 1 : 0);
  }
  final_linear<<<5, 256, 0, stream>>>(readout, Wm, bm, out);
}